// Round 10
// baseline (348.881 us; speedup 1.0000x reference)
//
#include <hip/hip_runtime.h>
#include <hip/hip_bf16.h>
#include <math.h>

#define N_NODES 50000
#define N_EDGES 800000
#define IN_DIM 32
#define HIDDEN 64
#define Z_DIM 32
#define SCAN_B 256
#define NB_SCAN ((N_NODES + SCAN_B - 1) / SCAN_B)   // 196

// bf16 (stored as ushort) <-> f32 helpers, RNE
__device__ __forceinline__ float bf2f(unsigned short u) {
    return __uint_as_float(((unsigned int)u) << 16);
}
__device__ __forceinline__ unsigned short f2bf(float f) {
    unsigned int u = __float_as_uint(f);
    u += 0x7fffu + ((u >> 16) & 1u);
    return (unsigned short)(u >> 16);
}

// ---------------------------------------------------------------------------
// prep: convert x to bf16, zero degree counters, detect edge_index dtype.
__global__ void prep_kernel(const float* __restrict__ x, unsigned short* __restrict__ xb,
                            const int* __restrict__ raw, int* __restrict__ flag,
                            int* __restrict__ cnt) {
    int i = blockIdx.x * 256 + threadIdx.x;
    if (i < N_NODES * IN_DIM) xb[i] = f2bf(x[i]);
    if (i < N_NODES) cnt[i] = 0;
    if (blockIdx.x == 0 && threadIdx.x < 64) {
        int odd = raw[2 * threadIdx.x + 1];
        unsigned long long b = __ballot(odd != 0);
        if (threadIdx.x == 0) *flag = (b == 0ULL) ? 1 : 0;
    }
}

// degree histogram, 2 edges/thread (2 independent atomic chains)
__global__ void hist_kernel(const void* __restrict__ raw, const int* __restrict__ flag,
                            int* __restrict__ cnt) {
    int e = (blockIdx.x * 256 + threadIdx.x) * 2;
    if (e >= N_EDGES) return;
    int d0, d1;
    bool has1 = (e + 1) < N_EDGES;
    if (*flag) {
        const long long* r = (const long long*)raw;
        d0 = (int)r[N_EDGES + e];
        d1 = has1 ? (int)r[N_EDGES + e + 1] : 0;
    } else {
        const int* r = (const int*)raw;
        d0 = r[N_EDGES + e];
        d1 = has1 ? r[N_EDGES + e + 1] : 0;
    }
    atomicAdd(&cnt[d0], 1);
    if (has1) atomicAdd(&cnt[d1], 1);
}

// ---------------------------------------------------------------------------
// 3-phase exclusive scan over cnt -> rowptr; also dinv = rsqrt(deg+1).
__global__ void scan1_kernel(const int* __restrict__ cnt, int* __restrict__ pre,
                             int* __restrict__ bsum, float* __restrict__ dinv) {
    __shared__ int s[SCAN_B];
    int t = threadIdx.x;
    int g = blockIdx.x * SCAN_B + t;
    int v = (g < N_NODES) ? cnt[g] : 0;
    if (g < N_NODES) dinv[g] = rsqrtf((float)(v + 1));   // +1 self loop
    s[t] = v;
    __syncthreads();
    for (int o = 1; o < SCAN_B; o <<= 1) {
        int add = (t >= o) ? s[t - o] : 0;
        __syncthreads();
        s[t] += add;
        __syncthreads();
    }
    if (g < N_NODES) pre[g] = s[t] - v;
    if (t == SCAN_B - 1) bsum[blockIdx.x] = s[t];
}

__global__ void scan2_kernel(int* __restrict__ bsum, int nb) {   // single block
    __shared__ int s[256];
    int t = threadIdx.x;
    int v = (t < nb) ? bsum[t] : 0;
    s[t] = v;
    __syncthreads();
    for (int o = 1; o < 256; o <<= 1) {
        int add = (t >= o) ? s[t - o] : 0;
        __syncthreads();
        s[t] += add;
        __syncthreads();
    }
    if (t < nb) bsum[t] = s[t] - v;
}

__global__ void scan3_kernel(int* __restrict__ rowptr, const int* __restrict__ bsum,
                             int* __restrict__ cursor) {
    int g = blockIdx.x * SCAN_B + threadIdx.x;
    if (g < N_NODES) {
        int r = rowptr[g] + bsum[blockIdx.x];
        rowptr[g] = r;
        cursor[g] = r;
    }
    if (g == 0) rowptr[N_NODES] = N_EDGES;
}

// counting-sort scatter, 2 edges/thread; emits packed (src, dinv[src]).
__global__ void scatter_kernel(const void* __restrict__ raw, const int* __restrict__ flag,
                               const float* __restrict__ dinv,
                               int* __restrict__ cursor, int2* __restrict__ ep) {
    int e = (blockIdx.x * 256 + threadIdx.x) * 2;
    if (e >= N_EDGES) return;
    int s0, d0, s1, d1;
    bool has1 = (e + 1) < N_EDGES;
    if (*flag) {
        const long long* r = (const long long*)raw;
        s0 = (int)r[e];
        d0 = (int)r[N_EDGES + e];
        s1 = has1 ? (int)r[e + 1] : 0;
        d1 = has1 ? (int)r[N_EDGES + e + 1] : 0;
    } else {
        const int* r = (const int*)raw;
        s0 = r[e];
        d0 = r[N_EDGES + e];
        s1 = has1 ? r[e + 1] : 0;
        d1 = has1 ? r[N_EDGES + e + 1] : 0;
    }
    float w0 = dinv[s0];
    float w1 = has1 ? dinv[s1] : 0.0f;
    int p0 = atomicAdd(&cursor[d0], 1);
    int p1 = has1 ? atomicAdd(&cursor[d1], 1) : 0;
    ep[p0] = make_int2(s0, __float_as_int(w0));
    if (has1) ep[p1] = make_int2(s1, __float_as_int(w1));
}

// ---------------------------------------------------------------------------
// Dense GEMM: out[v][lane] = sum_k in[v][k] * W[k][lane].  (bias lives in agg)
template<int DIN>
__global__ __launch_bounds__(256) void gemm_kernel(const unsigned short* __restrict__ in,
                                                   const float* __restrict__ W,
                                                   unsigned short* __restrict__ out) {
    int lane = threadIdx.x & 63;
    float wcol[DIN];
#pragma unroll
    for (int k = 0; k < DIN; k++) wcol[k] = W[k * 64 + lane];
    int wid = __builtin_amdgcn_readfirstlane((int)((blockIdx.x * blockDim.x + threadIdx.x) >> 6));
    int nw  = (gridDim.x * blockDim.x) >> 6;
    for (int v = wid; v < N_NODES; v += nw) {
        const uint4* rp = (const uint4*)(in + (size_t)v * DIN);   // uniform ptr
        float a0 = 0.0f, a1 = 0.0f;
#pragma unroll
        for (int c = 0; c < DIN / 8; c++) {
            uint4 r = rp[c];
            a0 = fmaf(__uint_as_float(r.x << 16),         wcol[c * 8 + 0], a0);
            a1 = fmaf(__uint_as_float(r.x & 0xffff0000u), wcol[c * 8 + 1], a1);
            a0 = fmaf(__uint_as_float(r.y << 16),         wcol[c * 8 + 2], a0);
            a1 = fmaf(__uint_as_float(r.y & 0xffff0000u), wcol[c * 8 + 3], a1);
            a0 = fmaf(__uint_as_float(r.z << 16),         wcol[c * 8 + 4], a0);
            a1 = fmaf(__uint_as_float(r.z & 0xffff0000u), wcol[c * 8 + 5], a1);
            a0 = fmaf(__uint_as_float(r.w << 16),         wcol[c * 8 + 6], a0);
            a1 = fmaf(__uint_as_float(r.w & 0xffff0000u), wcol[c * 8 + 7], a1);
        }
        out[(size_t)v * 64 + lane] = f2bf(a0 + a1);
    }
}

// Heads GEMM: out[v][lane] = h2[v][:] @ (lane<32 ? Wmu[:,lane] : Wlv[:,lane-32])
__global__ __launch_bounds__(256) void gemm_head_kernel(const unsigned short* __restrict__ in,
                                                        const float* __restrict__ Wmu,
                                                        const float* __restrict__ Wlv,
                                                        unsigned short* __restrict__ out) {
    int lane = threadIdx.x & 63;
    int f = lane & 31;
    float wcol[64];
#pragma unroll
    for (int k = 0; k < 64; k++)
        wcol[k] = (lane < 32) ? Wmu[k * 32 + f] : Wlv[k * 32 + f];
    int wid = __builtin_amdgcn_readfirstlane((int)((blockIdx.x * blockDim.x + threadIdx.x) >> 6));
    int nw  = (gridDim.x * blockDim.x) >> 6;
    for (int v = wid; v < N_NODES; v += nw) {
        const uint4* rp = (const uint4*)(in + (size_t)v * 64);
        float a0 = 0.0f, a1 = 0.0f;
#pragma unroll
        for (int c = 0; c < 8; c++) {
            uint4 r = rp[c];
            a0 = fmaf(__uint_as_float(r.x << 16),         wcol[c * 8 + 0], a0);
            a1 = fmaf(__uint_as_float(r.x & 0xffff0000u), wcol[c * 8 + 1], a1);
            a0 = fmaf(__uint_as_float(r.y << 16),         wcol[c * 8 + 2], a0);
            a1 = fmaf(__uint_as_float(r.y & 0xffff0000u), wcol[c * 8 + 3], a1);
            a0 = fmaf(__uint_as_float(r.z << 16),         wcol[c * 8 + 4], a0);
            a1 = fmaf(__uint_as_float(r.z & 0xffff0000u), wcol[c * 8 + 5], a1);
            a0 = fmaf(__uint_as_float(r.w << 16),         wcol[c * 8 + 6], a0);
            a1 = fmaf(__uint_as_float(r.w & 0xffff0000u), wcol[c * 8 + 7], a1);
        }
        out[(size_t)v * 64 + lane] = f2bf(a0 + a1);
    }
}

// ---------------------------------------------------------------------------
// Two-node aggregation core: acc[f] += sum_e w_e * g[s_e][f] for nodes va,vb
// processed with interleaved batches (2 latency chains, 16 loads in flight).
// lane = feature. Returns accA/accB (pre-scaled self-term must be added by
// caller before, bias/epilogue after).
__device__ __forceinline__ void agg_pair(int a0e, int a1e, int b0e, int b1e,
                                         const int2* __restrict__ ep,
                                         const unsigned short* __restrict__ g,
                                         int lane, float& accA, float& accB) {
    int ea = a0e, eb = b0e;
    while (ea < a1e || eb < b1e) {
        int ia = ea + lane; if (ia >= N_EDGES) ia = N_EDGES - 1;
        int ib = eb + lane; if (ib >= N_EDGES) ib = N_EDGES - 1;
        int2 prA = ep[ia];
        int2 prB = ep[ib];
        int cA = a1e - ea; cA = cA < 0 ? 0 : (cA > 64 ? 64 : cA);
        int cB = b1e - eb; cB = cB < 0 ? 0 : (cB > 64 ? 64 : cB);
        int cmin = cA < cB ? cA : cB;
        int j = 0;
        // joint chunks: 16 independent row loads in flight
        for (; j + 8 <= cmin; j += 8) {
            float fA[8], wA[8], fB[8], wB[8];
#pragma unroll
            for (int u = 0; u < 8; u++) {
                int jj = j + u;
                int sA = __builtin_amdgcn_readlane(prA.x, jj);
                int sB = __builtin_amdgcn_readlane(prB.x, jj);
                wA[u] = __int_as_float(__builtin_amdgcn_readlane(prA.y, jj));
                wB[u] = __int_as_float(__builtin_amdgcn_readlane(prB.y, jj));
                fA[u] = bf2f(g[(size_t)sA * 64 + lane]);
                fB[u] = bf2f(g[(size_t)sB * 64 + lane]);
            }
#pragma unroll
            for (int u = 0; u < 8; u++) {
                accA = fmaf(wA[u], fA[u], accA);
                accB = fmaf(wB[u], fB[u], accB);
            }
        }
        // A remainder (uniform-guarded chunks of 8)
        for (int jA = j; jA < cA; jA += 8) {
            float fA[8], wA[8];
#pragma unroll
            for (int u = 0; u < 8; u++) {
                int jj = jA + u;
                if (jj < cA) {
                    int sA = __builtin_amdgcn_readlane(prA.x, jj);
                    wA[u] = __int_as_float(__builtin_amdgcn_readlane(prA.y, jj));
                    fA[u] = bf2f(g[(size_t)sA * 64 + lane]);
                } else { wA[u] = 0.0f; fA[u] = 0.0f; }
            }
#pragma unroll
            for (int u = 0; u < 8; u++) accA = fmaf(wA[u], fA[u], accA);
        }
        // B remainder
        for (int jB = j; jB < cB; jB += 8) {
            float fB[8], wB[8];
#pragma unroll
            for (int u = 0; u < 8; u++) {
                int jj = jB + u;
                if (jj < cB) {
                    int sB = __builtin_amdgcn_readlane(prB.x, jj);
                    wB[u] = __int_as_float(__builtin_amdgcn_readlane(prB.y, jj));
                    fB[u] = bf2f(g[(size_t)sB * 64 + lane]);
                } else { wB[u] = 0.0f; fB[u] = 0.0f; }
            }
#pragma unroll
            for (int u = 0; u < 8; u++) accB = fmaf(wB[u], fB[u], accB);
        }
        ea += 64;
        eb += 64;
    }
}

// Aggregation, lane = feature: out[v][f] = relu(dv*(dv*g[v][f]+sum)+b[f]).
__global__ __launch_bounds__(256) void agg_layer_kernel(
        const int* __restrict__ rowptr, const int2* __restrict__ ep,
        const float* __restrict__ dinv, const unsigned short* __restrict__ g,
        const float* __restrict__ bias, unsigned short* __restrict__ out) {
    int lane = threadIdx.x & 63;
    float bb = bias[lane];
    int wid = __builtin_amdgcn_readfirstlane((int)((blockIdx.x * blockDim.x + threadIdx.x) >> 6));
    int nw  = (gridDim.x * blockDim.x) >> 6;
    for (int v = wid; v < N_NODES; v += 2 * nw) {
        int va = v, vb = v + nw;
        bool hasB = vb < N_NODES;
        int a0e = rowptr[va], a1e = rowptr[va + 1];
        int b0e = 0, b1e = 0;
        if (hasB) { b0e = rowptr[vb]; b1e = rowptr[vb + 1]; }
        float dvA = dinv[va];
        float dvB = hasB ? dinv[vb] : 0.0f;
        float accA = dvA * bf2f(g[(size_t)va * 64 + lane]);
        float accB = hasB ? dvB * bf2f(g[(size_t)vb * 64 + lane]) : 0.0f;
        agg_pair(a0e, a1e, b0e, b1e, ep, g, lane, accA, accB);
        out[(size_t)va * 64 + lane] = f2bf(fmaxf(dvA * accA + bb, 0.0f));
        if (hasB) out[(size_t)vb * 64 + lane] = f2bf(fmaxf(dvB * accB + bb, 0.0f));
    }
}

// Head aggregation + reparam. g packed [gmu | glv]; d_out = [z | mu | lv] fp32.
__global__ __launch_bounds__(256) void agg_head_kernel(
        const int* __restrict__ rowptr, const int2* __restrict__ ep,
        const float* __restrict__ dinv, const unsigned short* __restrict__ g,
        const float* __restrict__ bmu, const float* __restrict__ blv,
        const float* __restrict__ eps, float* __restrict__ outz) {
    int lane = threadIdx.x & 63;
    int f = lane & 31;
    bool hi = lane >= 32;
    float bb = hi ? blv[f] : bmu[f];
    float* z  = outz;
    float* mu = outz + (size_t)N_NODES * Z_DIM;
    float* lv = outz + 2 * (size_t)N_NODES * Z_DIM;
    int wid = __builtin_amdgcn_readfirstlane((int)((blockIdx.x * blockDim.x + threadIdx.x) >> 6));
    int nw  = (gridDim.x * blockDim.x) >> 6;
    for (int v = wid; v < N_NODES; v += 2 * nw) {
        int va = v, vb = v + nw;
        bool hasB = vb < N_NODES;
        int a0e = rowptr[va], a1e = rowptr[va + 1];
        int b0e = 0, b1e = 0;
        if (hasB) { b0e = rowptr[vb]; b1e = rowptr[vb + 1]; }
        float dvA = dinv[va];
        float dvB = hasB ? dinv[vb] : 0.0f;
        float accA = dvA * bf2f(g[(size_t)va * 64 + lane]);
        float accB = hasB ? dvB * bf2f(g[(size_t)vb * 64 + lane]) : 0.0f;
        agg_pair(a0e, a1e, b0e, b1e, ep, g, lane, accA, accB);
        {
            float m = dvA * accA + bb;
            float t = expf(0.5f * m) * eps[(size_t)va * Z_DIM + f];
            float tlo = __shfl(t, lane | 32);
            size_t o = (size_t)va * Z_DIM + f;
            if (!hi) { mu[o] = m; z[o] = m + tlo; }
            else     { lv[o] = m; }
        }
        if (hasB) {
            float m = dvB * accB + bb;
            float t = expf(0.5f * m) * eps[(size_t)vb * Z_DIM + f];
            float tlo = __shfl(t, lane | 32);
            size_t o = (size_t)vb * Z_DIM + f;
            if (!hi) { mu[o] = m; z[o] = m + tlo; }
            else     { lv[o] = m; }
        }
    }
}

// ---------------------------------------------------------------------------
extern "C" void kernel_launch(void* const* d_in, const int* in_sizes, int n_in,
                              void* d_out, int out_size, void* d_ws, size_t ws_size,
                              hipStream_t stream) {
    const float* x   = (const float*)d_in[0];
    const void*  ei  = d_in[1];
    const float* W1  = (const float*)d_in[2];
    const float* b1  = (const float*)d_in[3];
    const float* W2  = (const float*)d_in[4];
    const float* b2  = (const float*)d_in[5];
    const float* Wmu = (const float*)d_in[6];
    const float* bmu = (const float*)d_in[7];
    const float* Wlv = (const float*)d_in[8];
    const float* blv = (const float*)d_in[9];
    const float* eps = (const float*)d_in[10];
    float* out = (float*)d_out;
    (void)in_sizes; (void)n_in; (void)out_size; (void)ws_size;

    char* ws = (char*)d_ws;
    size_t off = 0;
    auto alloc = [&](size_t bytes) -> void* {
        void* p = ws + off;
        off += (bytes + 255) & ~(size_t)255;
        return p;
    };
    int2*           ep     = (int2*)alloc(sizeof(int2) * N_EDGES);   // 6.4 MB
    int*            rowptr = (int*)alloc(sizeof(int) * (N_NODES + 1));
    int*            cursor = (int*)alloc(sizeof(int) * N_NODES);
    int*            cnt    = (int*)alloc(sizeof(int) * N_NODES);
    float*          dinv   = (float*)alloc(sizeof(float) * N_NODES);
    int*            flag   = (int*)alloc(sizeof(int) * 64);
    int*            bsum   = (int*)alloc(sizeof(int) * 256);
    unsigned short* xb     = (unsigned short*)alloc(sizeof(short) * (size_t)N_NODES * IN_DIM);  // 3.2 MB
    unsigned short* G      = (unsigned short*)alloc(sizeof(short) * (size_t)N_NODES * HIDDEN);  // 6.4 MB
    unsigned short* H      = (unsigned short*)alloc(sizeof(short) * (size_t)N_NODES * HIDDEN);  // 6.4 MB

    prep_kernel<<<(N_NODES * IN_DIM + 255) / 256, 256, 0, stream>>>(x, xb, (const int*)ei, flag, cnt);
    hist_kernel<<<(N_EDGES / 2 + 255) / 256, 256, 0, stream>>>(ei, flag, cnt);
    scan1_kernel<<<NB_SCAN, SCAN_B, 0, stream>>>(cnt, rowptr, bsum, dinv);
    scan2_kernel<<<1, 256, 0, stream>>>(bsum, NB_SCAN);
    scan3_kernel<<<NB_SCAN, SCAN_B, 0, stream>>>(rowptr, bsum, cursor);
    scatter_kernel<<<(N_EDGES / 2 + 255) / 256, 256, 0, stream>>>(ei, flag, dinv, cursor, ep);

    const int FB = 2048;   // 8192 waves
    // Layer 1: g1 = x @ W1 ; h1 = relu(A g1 + b1)
    gemm_kernel<IN_DIM><<<FB, 256, 0, stream>>>(xb, W1, G);
    agg_layer_kernel<<<FB, 256, 0, stream>>>(rowptr, ep, dinv, G, b1, H);
    // Layer 2: g2 = h1 @ W2 ; h2 = relu(A g2 + b2)
    gemm_kernel<HIDDEN><<<FB, 256, 0, stream>>>(H, W2, G);
    agg_layer_kernel<<<FB, 256, 0, stream>>>(rowptr, ep, dinv, G, b2, H);
    // Heads: gH = h2 @ [Wmu|Wlv] ; [mu|lv] = A gH + b ; z = mu + exp(.5 lv) eps
    gemm_head_kernel<<<FB, 256, 0, stream>>>(H, Wmu, Wlv, G);
    agg_head_kernel<<<FB, 256, 0, stream>>>(rowptr, ep, dinv, G, bmu, blv, eps, out);
}

// Round 11
// 313.791 us; speedup vs baseline: 1.1118x; 1.1118x over previous
//
#include <hip/hip_runtime.h>
#include <hip/hip_bf16.h>
#include <math.h>

#define N_NODES 50000
#define N_EDGES 800000
#define IN_DIM 32
#define HIDDEN 64
#define Z_DIM 32
#define SCAN_B 256
#define NB_SCAN ((N_NODES + SCAN_B - 1) / SCAN_B)   // 196

// bf16 (stored as ushort) <-> f32 helpers, RNE
__device__ __forceinline__ float bf2f(unsigned short u) {
    return __uint_as_float(((unsigned int)u) << 16);
}
__device__ __forceinline__ unsigned short f2bf(float f) {
    unsigned int u = __float_as_uint(f);
    u += 0x7fffu + ((u >> 16) & 1u);
    return (unsigned short)(u >> 16);
}

// ---------------------------------------------------------------------------
// prep: convert x to bf16, zero degree counters, detect edge_index dtype.
__global__ void prep_kernel(const float* __restrict__ x, unsigned short* __restrict__ xb,
                            const int* __restrict__ raw, int* __restrict__ flag,
                            int* __restrict__ cnt) {
    int i = blockIdx.x * 256 + threadIdx.x;
    if (i < N_NODES * IN_DIM) xb[i] = f2bf(x[i]);
    if (i < N_NODES) cnt[i] = 0;
    if (blockIdx.x == 0 && threadIdx.x < 64) {
        int odd = raw[2 * threadIdx.x + 1];
        unsigned long long b = __ballot(odd != 0);
        if (threadIdx.x == 0) *flag = (b == 0ULL) ? 1 : 0;
    }
}

// degree histogram straight off the raw edge_index (uniform branch on dtype)
__global__ void hist_kernel(const void* __restrict__ raw, const int* __restrict__ flag,
                            int* __restrict__ cnt) {
    int e = blockIdx.x * 256 + threadIdx.x;
    if (e >= N_EDGES) return;
    int d = (*flag) ? (int)((const long long*)raw)[N_EDGES + e]
                    : ((const int*)raw)[N_EDGES + e];
    atomicAdd(&cnt[d], 1);
}

// ---------------------------------------------------------------------------
// 3-phase exclusive scan over cnt -> rowptr; also dinv = rsqrt(deg+1).
__global__ void scan1_kernel(const int* __restrict__ cnt, int* __restrict__ pre,
                             int* __restrict__ bsum, float* __restrict__ dinv) {
    __shared__ int s[SCAN_B];
    int t = threadIdx.x;
    int g = blockIdx.x * SCAN_B + t;
    int v = (g < N_NODES) ? cnt[g] : 0;
    if (g < N_NODES) dinv[g] = rsqrtf((float)(v + 1));   // +1 self loop
    s[t] = v;
    __syncthreads();
    for (int o = 1; o < SCAN_B; o <<= 1) {
        int add = (t >= o) ? s[t - o] : 0;
        __syncthreads();
        s[t] += add;
        __syncthreads();
    }
    if (g < N_NODES) pre[g] = s[t] - v;
    if (t == SCAN_B - 1) bsum[blockIdx.x] = s[t];
}

__global__ void scan2_kernel(int* __restrict__ bsum, int nb) {   // single block
    __shared__ int s[256];
    int t = threadIdx.x;
    int v = (t < nb) ? bsum[t] : 0;
    s[t] = v;
    __syncthreads();
    for (int o = 1; o < 256; o <<= 1) {
        int add = (t >= o) ? s[t - o] : 0;
        __syncthreads();
        s[t] += add;
        __syncthreads();
    }
    if (t < nb) bsum[t] = s[t] - v;
}

__global__ void scan3_kernel(int* __restrict__ rowptr, const int* __restrict__ bsum,
                             int* __restrict__ cursor) {
    int g = blockIdx.x * SCAN_B + threadIdx.x;
    if (g < N_NODES) {
        int r = rowptr[g] + bsum[blockIdx.x];
        rowptr[g] = r;
        cursor[g] = r;
    }
    if (g == 0) rowptr[N_NODES] = N_EDGES;
}

// counting-sort scatter; packed (src, dinv[src]) via nontemporal 8B store
// (bypass L2 line ownership churn on random writes).
__global__ void scatter_kernel(const void* __restrict__ raw, const int* __restrict__ flag,
                               const float* __restrict__ dinv,
                               int* __restrict__ cursor, int2* __restrict__ ep) {
    int e = blockIdx.x * 256 + threadIdx.x;
    if (e >= N_EDGES) return;
    int s, d;
    if (*flag) {
        s = (int)((const long long*)raw)[e];
        d = (int)((const long long*)raw)[N_EDGES + e];
    } else {
        s = ((const int*)raw)[e];
        d = ((const int*)raw)[N_EDGES + e];
    }
    unsigned long long packed = ((unsigned long long)(unsigned int)__float_as_int(dinv[s]) << 32)
                              | (unsigned long long)(unsigned int)s;
    int p = atomicAdd(&cursor[d], 1);
    __builtin_nontemporal_store(packed, (unsigned long long*)&ep[p]);
}

// ---------------------------------------------------------------------------
// Dense GEMM: out[v][lane] = sum_k in[v][k] * W[k][lane].  (bias lives in agg)
template<int DIN>
__global__ __launch_bounds__(256) void gemm_kernel(const unsigned short* __restrict__ in,
                                                   const float* __restrict__ W,
                                                   unsigned short* __restrict__ out) {
    int lane = threadIdx.x & 63;
    float wcol[DIN];
#pragma unroll
    for (int k = 0; k < DIN; k++) wcol[k] = W[k * 64 + lane];
    int wid = __builtin_amdgcn_readfirstlane((int)((blockIdx.x * blockDim.x + threadIdx.x) >> 6));
    int nw  = (gridDim.x * blockDim.x) >> 6;
    for (int v = wid; v < N_NODES; v += nw) {
        const uint4* rp = (const uint4*)(in + (size_t)v * DIN);   // uniform ptr
        float a0 = 0.0f, a1 = 0.0f;
#pragma unroll
        for (int c = 0; c < DIN / 8; c++) {
            uint4 r = rp[c];
            a0 = fmaf(__uint_as_float(r.x << 16),         wcol[c * 8 + 0], a0);
            a1 = fmaf(__uint_as_float(r.x & 0xffff0000u), wcol[c * 8 + 1], a1);
            a0 = fmaf(__uint_as_float(r.y << 16),         wcol[c * 8 + 2], a0);
            a1 = fmaf(__uint_as_float(r.y & 0xffff0000u), wcol[c * 8 + 3], a1);
            a0 = fmaf(__uint_as_float(r.z << 16),         wcol[c * 8 + 4], a0);
            a1 = fmaf(__uint_as_float(r.z & 0xffff0000u), wcol[c * 8 + 5], a1);
            a0 = fmaf(__uint_as_float(r.w << 16),         wcol[c * 8 + 6], a0);
            a1 = fmaf(__uint_as_float(r.w & 0xffff0000u), wcol[c * 8 + 7], a1);
        }
        out[(size_t)v * 64 + lane] = f2bf(a0 + a1);
    }
}

// Heads GEMM: out[v][lane] = h2[v][:] @ (lane<32 ? Wmu[:,lane] : Wlv[:,lane-32])
__global__ __launch_bounds__(256) void gemm_head_kernel(const unsigned short* __restrict__ in,
                                                        const float* __restrict__ Wmu,
                                                        const float* __restrict__ Wlv,
                                                        unsigned short* __restrict__ out) {
    int lane = threadIdx.x & 63;
    int f = lane & 31;
    float wcol[64];
#pragma unroll
    for (int k = 0; k < 64; k++)
        wcol[k] = (lane < 32) ? Wmu[k * 32 + f] : Wlv[k * 32 + f];
    int wid = __builtin_amdgcn_readfirstlane((int)((blockIdx.x * blockDim.x + threadIdx.x) >> 6));
    int nw  = (gridDim.x * blockDim.x) >> 6;
    for (int v = wid; v < N_NODES; v += nw) {
        const uint4* rp = (const uint4*)(in + (size_t)v * 64);
        float a0 = 0.0f, a1 = 0.0f;
#pragma unroll
        for (int c = 0; c < 8; c++) {
            uint4 r = rp[c];
            a0 = fmaf(__uint_as_float(r.x << 16),         wcol[c * 8 + 0], a0);
            a1 = fmaf(__uint_as_float(r.x & 0xffff0000u), wcol[c * 8 + 1], a1);
            a0 = fmaf(__uint_as_float(r.y << 16),         wcol[c * 8 + 2], a0);
            a1 = fmaf(__uint_as_float(r.y & 0xffff0000u), wcol[c * 8 + 3], a1);
            a0 = fmaf(__uint_as_float(r.z << 16),         wcol[c * 8 + 4], a0);
            a1 = fmaf(__uint_as_float(r.z & 0xffff0000u), wcol[c * 8 + 5], a1);
            a0 = fmaf(__uint_as_float(r.w << 16),         wcol[c * 8 + 6], a0);
            a1 = fmaf(__uint_as_float(r.w & 0xffff0000u), wcol[c * 8 + 7], a1);
        }
        out[(size_t)v * 64 + lane] = f2bf(a0 + a1);
    }
}

// ---------------------------------------------------------------------------
// Single-node aggregation body: acc[lane] += sum_e w_e * g[src_e][lane].
// 16-deep main chunks (16 independent row loads in flight), masked-8 tail
// with select-based weights (no divergent branches; all loads to valid addrs).
__device__ __forceinline__ float agg_sum(int e0, int e1, const int2* __restrict__ ep,
                                         const unsigned short* __restrict__ g,
                                         int lane, float acc) {
    for (int base = e0; base < e1; base += 64) {
        int idx = base + lane;
        int2 pr = ep[idx < N_EDGES ? idx : (N_EDGES - 1)];   // 64 edges, coalesced
        int cnt = e1 - base; cnt = cnt > 64 ? 64 : cnt;      // uniform
        int j = 0;
        for (; j + 16 <= cnt; j += 16) {                     // full 16-chunks
            float f[16], w[16];
#pragma unroll
            for (int u = 0; u < 16; u++) {
                int jj = j + u;
                int   s = __builtin_amdgcn_readlane(pr.x, jj);
                w[u]    = __int_as_float(__builtin_amdgcn_readlane(pr.y, jj));
                f[u]    = bf2f(g[(size_t)s * 64 + lane]);
            }
#pragma unroll
            for (int u = 0; u < 16; u++) acc = fmaf(w[u], f[u], acc);
        }
        for (; j < cnt; j += 8) {                            // masked 8-tail
            float f[8], w[8];
#pragma unroll
            for (int u = 0; u < 8; u++) {
                int jj = j + u;
                int   s = __builtin_amdgcn_readlane(pr.x, jj < 63 ? jj : 63);
                float wv = __int_as_float(__builtin_amdgcn_readlane(pr.y, jj < 63 ? jj : 63));
                w[u]    = (jj < cnt) ? wv : 0.0f;            // uniform select
                f[u]    = bf2f(g[(size_t)s * 64 + lane]);
            }
#pragma unroll
            for (int u = 0; u < 8; u++) acc = fmaf(w[u], f[u], acc);
        }
    }
    return acc;
}

// Aggregation, lane = feature: out[v][f] = relu(dv*(dv*g[v][f]+sum)+b[f]).
__global__ __launch_bounds__(256) void agg_layer_kernel(
        const int* __restrict__ rowptr, const int2* __restrict__ ep,
        const float* __restrict__ dinv, const unsigned short* __restrict__ g,
        const float* __restrict__ bias, unsigned short* __restrict__ out) {
    int lane = threadIdx.x & 63;
    float bb = bias[lane];
    int wid = __builtin_amdgcn_readfirstlane((int)((blockIdx.x * blockDim.x + threadIdx.x) >> 6));
    int nw  = (gridDim.x * blockDim.x) >> 6;
    for (int v = wid; v < N_NODES; v += nw) {
        int e0 = rowptr[v], e1 = rowptr[v + 1];     // uniform
        float dv = dinv[v];
        float acc = dv * bf2f(g[(size_t)v * 64 + lane]);
        acc = agg_sum(e0, e1, ep, g, lane, acc);
        out[(size_t)v * 64 + lane] = f2bf(fmaxf(dv * acc + bb, 0.0f));
    }
}

// Head aggregation + reparam. g packed [gmu | glv]; d_out = [z | mu | lv] fp32.
__global__ __launch_bounds__(256) void agg_head_kernel(
        const int* __restrict__ rowptr, const int2* __restrict__ ep,
        const float* __restrict__ dinv, const unsigned short* __restrict__ g,
        const float* __restrict__ bmu, const float* __restrict__ blv,
        const float* __restrict__ eps, float* __restrict__ outz) {
    int lane = threadIdx.x & 63;
    int f = lane & 31;
    bool hi = lane >= 32;
    float bb = hi ? blv[f] : bmu[f];
    float* z  = outz;
    float* mu = outz + (size_t)N_NODES * Z_DIM;
    float* lv = outz + 2 * (size_t)N_NODES * Z_DIM;
    int wid = __builtin_amdgcn_readfirstlane((int)((blockIdx.x * blockDim.x + threadIdx.x) >> 6));
    int nw  = (gridDim.x * blockDim.x) >> 6;
    for (int v = wid; v < N_NODES; v += nw) {
        int e0 = rowptr[v], e1 = rowptr[v + 1];
        float dv = dinv[v];
        float acc = dv * bf2f(g[(size_t)v * 64 + lane]);
        acc = agg_sum(e0, e1, ep, g, lane, acc);
        float m = dv * acc + bb;                    // mu (lanes<32) / lv (hi)
        float t = expf(0.5f * m) * eps[(size_t)v * Z_DIM + f];
        float tlo = __shfl(t, lane | 32);
        size_t o = (size_t)v * Z_DIM + f;
        if (!hi) { mu[o] = m; z[o] = m + tlo; }
        else     { lv[o] = m; }
    }
}

// ---------------------------------------------------------------------------
extern "C" void kernel_launch(void* const* d_in, const int* in_sizes, int n_in,
                              void* d_out, int out_size, void* d_ws, size_t ws_size,
                              hipStream_t stream) {
    const float* x   = (const float*)d_in[0];
    const void*  ei  = d_in[1];
    const float* W1  = (const float*)d_in[2];
    const float* b1  = (const float*)d_in[3];
    const float* W2  = (const float*)d_in[4];
    const float* b2  = (const float*)d_in[5];
    const float* Wmu = (const float*)d_in[6];
    const float* bmu = (const float*)d_in[7];
    const float* Wlv = (const float*)d_in[8];
    const float* blv = (const float*)d_in[9];
    const float* eps = (const float*)d_in[10];
    float* out = (float*)d_out;
    (void)in_sizes; (void)n_in; (void)out_size; (void)ws_size;

    char* ws = (char*)d_ws;
    size_t off = 0;
    auto alloc = [&](size_t bytes) -> void* {
        void* p = ws + off;
        off += (bytes + 255) & ~(size_t)255;
        return p;
    };
    int2*           ep     = (int2*)alloc(sizeof(int2) * N_EDGES);   // 6.4 MB
    int*            rowptr = (int*)alloc(sizeof(int) * (N_NODES + 1));
    int*            cursor = (int*)alloc(sizeof(int) * N_NODES);
    int*            cnt    = (int*)alloc(sizeof(int) * N_NODES);
    float*          dinv   = (float*)alloc(sizeof(float) * N_NODES);
    int*            flag   = (int*)alloc(sizeof(int) * 64);
    int*            bsum   = (int*)alloc(sizeof(int) * 256);
    unsigned short* xb     = (unsigned short*)alloc(sizeof(short) * (size_t)N_NODES * IN_DIM);  // 3.2 MB
    unsigned short* G      = (unsigned short*)alloc(sizeof(short) * (size_t)N_NODES * HIDDEN);  // 6.4 MB
    unsigned short* H      = (unsigned short*)alloc(sizeof(short) * (size_t)N_NODES * HIDDEN);  // 6.4 MB

    prep_kernel<<<(N_NODES * IN_DIM + 255) / 256, 256, 0, stream>>>(x, xb, (const int*)ei, flag, cnt);
    hist_kernel<<<(N_EDGES + 255) / 256, 256, 0, stream>>>(ei, flag, cnt);
    scan1_kernel<<<NB_SCAN, SCAN_B, 0, stream>>>(cnt, rowptr, bsum, dinv);
    scan2_kernel<<<1, 256, 0, stream>>>(bsum, NB_SCAN);
    scan3_kernel<<<NB_SCAN, SCAN_B, 0, stream>>>(rowptr, bsum, cursor);
    scatter_kernel<<<(N_EDGES + 255) / 256, 256, 0, stream>>>(ei, flag, dinv, cursor, ep);

    const int FB = 2048;   // 8192 waves
    // Layer 1: g1 = x @ W1 ; h1 = relu(A g1 + b1)
    gemm_kernel<IN_DIM><<<FB, 256, 0, stream>>>(xb, W1, G);
    agg_layer_kernel<<<FB, 256, 0, stream>>>(rowptr, ep, dinv, G, b1, H);
    // Layer 2: g2 = h1 @ W2 ; h2 = relu(A g2 + b2)
    gemm_kernel<HIDDEN><<<FB, 256, 0, stream>>>(H, W2, G);
    agg_layer_kernel<<<FB, 256, 0, stream>>>(rowptr, ep, dinv, G, b2, H);
    // Heads: gH = h2 @ [Wmu|Wlv] ; [mu|lv] = A gH + b ; z = mu + exp(.5 lv) eps
    gemm_head_kernel<<<FB, 256, 0, stream>>>(H, Wmu, Wlv, G);
    agg_head_kernel<<<FB, 256, 0, stream>>>(rowptr, ep, dinv, G, bmu, blv, eps, out);
}

// Round 12
// 312.777 us; speedup vs baseline: 1.1154x; 1.0032x over previous
//
#include <hip/hip_runtime.h>
#include <hip/hip_bf16.h>
#include <math.h>

#define N_NODES 50000
#define N_EDGES 800000
#define IN_DIM 32
#define HIDDEN 64
#define Z_DIM 32
#define SCAN_B 256
#define NB_SCAN ((N_NODES + SCAN_B - 1) / SCAN_B)   // 196
#define SCAT_B ((N_EDGES + 255) / 256)              // 3125 scatter blocks
#define FB 2048                                     // 8192 waves for node kernels

// bf16 (stored as ushort) <-> f32 helpers, RNE
__device__ __forceinline__ float bf2f(unsigned short u) {
    return __uint_as_float(((unsigned int)u) << 16);
}
__device__ __forceinline__ unsigned short f2bf(float f) {
    unsigned int u = __float_as_uint(f);
    u += 0x7fffu + ((u >> 16) & 1u);
    return (unsigned short)(u >> 16);
}

// wave-local edge dtype detect: int64 LE values < 2^31 have all-zero odd words.
__device__ __forceinline__ int detect64(const int* raw) {
    int lane = threadIdx.x & 63;
    int odd = raw[2 * lane + 1];
    unsigned long long b = __ballot(odd != 0);
    return (b == 0ULL) ? 1 : 0;
}

// ---------------------------------------------------------------------------
// prep: x->bf16 convert + degree histogram (cnt pre-zeroed by memsetAsync)
// + publish dtype flag. Each wave derives the flag locally (no dependency).
__global__ void prep_kernel(const float* __restrict__ x, unsigned short* __restrict__ xb,
                            const void* __restrict__ raw, int* __restrict__ flag,
                            int* __restrict__ cnt) {
    int is64 = detect64((const int*)raw);
    int i = blockIdx.x * 256 + threadIdx.x;
    if (blockIdx.x == 0 && threadIdx.x == 0) *flag = is64;
    if (i < N_NODES * IN_DIM) xb[i] = f2bf(x[i]);
    if (i < N_EDGES) {
        int d = is64 ? (int)((const long long*)raw)[N_EDGES + i]
                     : ((const int*)raw)[N_EDGES + i];
        atomicAdd(&cnt[d], 1);
    }
}

// ---------------------------------------------------------------------------
// scan1: block-local exclusive scan of cnt -> pre (into rowptr array),
// block sums -> bsum, dinv = rsqrt(deg+1).
__global__ void scan1_kernel(const int* __restrict__ cnt, int* __restrict__ pre,
                             int* __restrict__ bsum, float* __restrict__ dinv) {
    __shared__ int s[SCAN_B];
    int t = threadIdx.x;
    int g = blockIdx.x * SCAN_B + t;
    int v = (g < N_NODES) ? cnt[g] : 0;
    if (g < N_NODES) dinv[g] = rsqrtf((float)(v + 1));   // +1 self loop
    s[t] = v;
    __syncthreads();
    for (int o = 1; o < SCAN_B; o <<= 1) {
        int add = (t >= o) ? s[t - o] : 0;
        __syncthreads();
        s[t] += add;
        __syncthreads();
    }
    if (g < N_NODES) pre[g] = s[t] - v;
    if (t == SCAN_B - 1) bsum[blockIdx.x] = s[t];
}

// scan23: each block redundantly scans the 196 bsums in LDS, then applies its
// own exclusive offset to pre -> rowptr (+ cursor copy).
__global__ void scan23_kernel(int* __restrict__ rowptr, const int* __restrict__ bsum,
                              int* __restrict__ cursor) {
    __shared__ int s[256];
    int t = threadIdx.x;
    int v = (t < NB_SCAN) ? bsum[t] : 0;
    s[t] = v;
    __syncthreads();
    for (int o = 1; o < 256; o <<= 1) {
        int add = (t >= o) ? s[t - o] : 0;
        __syncthreads();
        s[t] += add;
        __syncthreads();
    }
    int excl = s[blockIdx.x] - bsum[blockIdx.x];         // exclusive offset
    int g = blockIdx.x * SCAN_B + t;
    if (g < N_NODES) {
        int r = rowptr[g] + excl;
        rowptr[g] = r;
        cursor[g] = r;
    }
    if (g == 0) rowptr[N_NODES] = N_EDGES;
}

// ---------------------------------------------------------------------------
// Fused scatter + gemm1 (independent work; block-role split).
// Blocks [0, SCAT_B): counting-sort scatter of (src, dinv[src]).
// Blocks [SCAT_B, SCAT_B+FB): g1 = xb @ W1 (lane = out feature).
__global__ __launch_bounds__(256) void scatter_gemm1_kernel(
        const void* __restrict__ raw, const int* __restrict__ flag,
        const float* __restrict__ dinv, int* __restrict__ cursor,
        int2* __restrict__ ep,
        const unsigned short* __restrict__ xb, const float* __restrict__ W1,
        unsigned short* __restrict__ G) {
    if (blockIdx.x < SCAT_B) {
        int e = blockIdx.x * 256 + threadIdx.x;
        if (e >= N_EDGES) return;
        int s, d;
        if (*flag) {
            s = (int)((const long long*)raw)[e];
            d = (int)((const long long*)raw)[N_EDGES + e];
        } else {
            s = ((const int*)raw)[e];
            d = ((const int*)raw)[N_EDGES + e];
        }
        float w = dinv[s];
        int p = atomicAdd(&cursor[d], 1);
        ep[p] = make_int2(s, __float_as_int(w));
    } else {
        int lane = threadIdx.x & 63;
        float wcol[IN_DIM];
#pragma unroll
        for (int k = 0; k < IN_DIM; k++) wcol[k] = W1[k * 64 + lane];
        int bid = blockIdx.x - SCAT_B;
        int wid = __builtin_amdgcn_readfirstlane((int)((bid * 256 + threadIdx.x) >> 6));
        int nw  = (FB * 256) >> 6;
        for (int v = wid; v < N_NODES; v += nw) {
            const uint4* rp = (const uint4*)(xb + (size_t)v * IN_DIM);
            float a0 = 0.0f, a1 = 0.0f;
#pragma unroll
            for (int c = 0; c < IN_DIM / 8; c++) {
                uint4 r = rp[c];
                a0 = fmaf(__uint_as_float(r.x << 16),         wcol[c * 8 + 0], a0);
                a1 = fmaf(__uint_as_float(r.x & 0xffff0000u), wcol[c * 8 + 1], a1);
                a0 = fmaf(__uint_as_float(r.y << 16),         wcol[c * 8 + 2], a0);
                a1 = fmaf(__uint_as_float(r.y & 0xffff0000u), wcol[c * 8 + 3], a1);
                a0 = fmaf(__uint_as_float(r.z << 16),         wcol[c * 8 + 4], a0);
                a1 = fmaf(__uint_as_float(r.z & 0xffff0000u), wcol[c * 8 + 5], a1);
                a0 = fmaf(__uint_as_float(r.w << 16),         wcol[c * 8 + 6], a0);
                a1 = fmaf(__uint_as_float(r.w & 0xffff0000u), wcol[c * 8 + 7], a1);
            }
            G[(size_t)v * 64 + lane] = f2bf(a0 + a1);
        }
    }
}

// ---------------------------------------------------------------------------
// Dense GEMM: out[v][lane] = sum_k in[v][k] * W[k][lane].  (bias lives in agg)
template<int DIN>
__global__ __launch_bounds__(256) void gemm_kernel(const unsigned short* __restrict__ in,
                                                   const float* __restrict__ W,
                                                   unsigned short* __restrict__ out) {
    int lane = threadIdx.x & 63;
    float wcol[DIN];
#pragma unroll
    for (int k = 0; k < DIN; k++) wcol[k] = W[k * 64 + lane];
    int wid = __builtin_amdgcn_readfirstlane((int)((blockIdx.x * blockDim.x + threadIdx.x) >> 6));
    int nw  = (gridDim.x * blockDim.x) >> 6;
    for (int v = wid; v < N_NODES; v += nw) {
        const uint4* rp = (const uint4*)(in + (size_t)v * DIN);   // uniform ptr
        float a0 = 0.0f, a1 = 0.0f;
#pragma unroll
        for (int c = 0; c < DIN / 8; c++) {
            uint4 r = rp[c];
            a0 = fmaf(__uint_as_float(r.x << 16),         wcol[c * 8 + 0], a0);
            a1 = fmaf(__uint_as_float(r.x & 0xffff0000u), wcol[c * 8 + 1], a1);
            a0 = fmaf(__uint_as_float(r.y << 16),         wcol[c * 8 + 2], a0);
            a1 = fmaf(__uint_as_float(r.y & 0xffff0000u), wcol[c * 8 + 3], a1);
            a0 = fmaf(__uint_as_float(r.z << 16),         wcol[c * 8 + 4], a0);
            a1 = fmaf(__uint_as_float(r.z & 0xffff0000u), wcol[c * 8 + 5], a1);
            a0 = fmaf(__uint_as_float(r.w << 16),         wcol[c * 8 + 6], a0);
            a1 = fmaf(__uint_as_float(r.w & 0xffff0000u), wcol[c * 8 + 7], a1);
        }
        out[(size_t)v * 64 + lane] = f2bf(a0 + a1);
    }
}

// Heads GEMM: out[v][lane] = h2[v][:] @ (lane<32 ? Wmu[:,lane] : Wlv[:,lane-32])
__global__ __launch_bounds__(256) void gemm_head_kernel(const unsigned short* __restrict__ in,
                                                        const float* __restrict__ Wmu,
                                                        const float* __restrict__ Wlv,
                                                        unsigned short* __restrict__ out) {
    int lane = threadIdx.x & 63;
    int f = lane & 31;
    float wcol[64];
#pragma unroll
    for (int k = 0; k < 64; k++)
        wcol[k] = (lane < 32) ? Wmu[k * 32 + f] : Wlv[k * 32 + f];
    int wid = __builtin_amdgcn_readfirstlane((int)((blockIdx.x * blockDim.x + threadIdx.x) >> 6));
    int nw  = (gridDim.x * blockDim.x) >> 6;
    for (int v = wid; v < N_NODES; v += nw) {
        const uint4* rp = (const uint4*)(in + (size_t)v * 64);
        float a0 = 0.0f, a1 = 0.0f;
#pragma unroll
        for (int c = 0; c < 8; c++) {
            uint4 r = rp[c];
            a0 = fmaf(__uint_as_float(r.x << 16),         wcol[c * 8 + 0], a0);
            a1 = fmaf(__uint_as_float(r.x & 0xffff0000u), wcol[c * 8 + 1], a1);
            a0 = fmaf(__uint_as_float(r.y << 16),         wcol[c * 8 + 2], a0);
            a1 = fmaf(__uint_as_float(r.y & 0xffff0000u), wcol[c * 8 + 3], a1);
            a0 = fmaf(__uint_as_float(r.z << 16),         wcol[c * 8 + 4], a0);
            a1 = fmaf(__uint_as_float(r.z & 0xffff0000u), wcol[c * 8 + 5], a1);
            a0 = fmaf(__uint_as_float(r.w << 16),         wcol[c * 8 + 6], a0);
            a1 = fmaf(__uint_as_float(r.w & 0xffff0000u), wcol[c * 8 + 7], a1);
        }
        out[(size_t)v * 64 + lane] = f2bf(a0 + a1);
    }
}

// ---------------------------------------------------------------------------
// Process one node's edges given a prefetched first ep batch pr0.
// 16-deep main chunks, masked-8 tail (guard-free), extra batches inline.
__device__ __forceinline__ float agg_node(int e0, int e1, int2 pr0,
                                          const int2* __restrict__ ep,
                                          const unsigned short* __restrict__ g,
                                          int lane, float acc) {
    int2 pr = pr0;
    for (int base = e0; base < e1; base += 64) {
        int cnt = e1 - base; cnt = cnt > 64 ? 64 : cnt;      // uniform
        int j = 0;
        for (; j + 16 <= cnt; j += 16) {                     // full 16-chunks
            float f[16], w[16];
#pragma unroll
            for (int u = 0; u < 16; u++) {
                int jj = j + u;
                int   s = __builtin_amdgcn_readlane(pr.x, jj);
                w[u]    = __int_as_float(__builtin_amdgcn_readlane(pr.y, jj));
                f[u]    = bf2f(g[(size_t)s * 64 + lane]);
            }
#pragma unroll
            for (int u = 0; u < 16; u++) acc = fmaf(w[u], f[u], acc);
        }
        for (; j < cnt; j += 8) {                            // masked 8-tail
            float f[8], w[8];
#pragma unroll
            for (int u = 0; u < 8; u++) {
                int jj = j + u;
                int   s = __builtin_amdgcn_readlane(pr.x, jj < 63 ? jj : 63);
                float wv = __int_as_float(__builtin_amdgcn_readlane(pr.y, jj < 63 ? jj : 63));
                w[u]    = (jj < cnt) ? wv : 0.0f;            // uniform select
                f[u]    = bf2f(g[(size_t)s * 64 + lane]);
            }
#pragma unroll
            for (int u = 0; u < 8; u++) acc = fmaf(w[u], f[u], acc);
        }
        int nb = base + 64;
        if (nb < e1) {                                       // rare extra batch
            int idx = nb + lane;
            pr = ep[idx < N_EDGES ? idx : (N_EDGES - 1)];
        }
    }
    return acc;
}

// Aggregation with next-node software pipeline: prefetch rowptr/dinv/self-row/
// first ep batch for node v+nw while processing node v.
__global__ __launch_bounds__(256) void agg_layer_kernel(
        const int* __restrict__ rowptr, const int2* __restrict__ ep,
        const float* __restrict__ dinv, const unsigned short* __restrict__ g,
        const float* __restrict__ bias, unsigned short* __restrict__ out) {
    int lane = threadIdx.x & 63;
    float bb = bias[lane];
    int wid = __builtin_amdgcn_readfirstlane((int)((blockIdx.x * blockDim.x + threadIdx.x) >> 6));
    int nw  = (gridDim.x * blockDim.x) >> 6;
    int v = wid;
    if (v >= N_NODES) return;
    int e0 = rowptr[v], e1 = rowptr[v + 1];
    float dv = dinv[v];
    float hv = bf2f(g[(size_t)v * 64 + lane]);
    int i0 = e0 + lane;
    int2 pr = ep[i0 < N_EDGES ? i0 : (N_EDGES - 1)];
    while (v < N_NODES) {
        int vn = v + nw;
        int e0n = 0, e1n = 0;
        float dvn = 0.0f, hvn = 0.0f;
        int2 prn = make_int2(0, 0);
        if (vn < N_NODES) {                                  // prefetch next node
            e0n = rowptr[vn]; e1n = rowptr[vn + 1];
            dvn = dinv[vn];
            hvn = bf2f(g[(size_t)vn * 64 + lane]);
            int in0 = e0n + lane;
            prn = ep[in0 < N_EDGES ? in0 : (N_EDGES - 1)];
        }
        float acc = dv * hv;
        acc = agg_node(e0, e1, pr, ep, g, lane, acc);
        out[(size_t)v * 64 + lane] = f2bf(fmaxf(dv * acc + bb, 0.0f));
        v = vn; e0 = e0n; e1 = e1n; dv = dvn; hv = hvn; pr = prn;
    }
}

// Head aggregation + reparam. g packed [gmu | glv]; d_out = [z | mu | lv] fp32.
__global__ __launch_bounds__(256) void agg_head_kernel(
        const int* __restrict__ rowptr, const int2* __restrict__ ep,
        const float* __restrict__ dinv, const unsigned short* __restrict__ g,
        const float* __restrict__ bmu, const float* __restrict__ blv,
        const float* __restrict__ eps, float* __restrict__ outz) {
    int lane = threadIdx.x & 63;
    int f = lane & 31;
    bool hi = lane >= 32;
    float bb = hi ? blv[f] : bmu[f];
    float* z  = outz;
    float* mu = outz + (size_t)N_NODES * Z_DIM;
    float* lv = outz + 2 * (size_t)N_NODES * Z_DIM;
    int wid = __builtin_amdgcn_readfirstlane((int)((blockIdx.x * blockDim.x + threadIdx.x) >> 6));
    int nw  = (gridDim.x * blockDim.x) >> 6;
    int v = wid;
    if (v >= N_NODES) return;
    int e0 = rowptr[v], e1 = rowptr[v + 1];
    float dv = dinv[v];
    float hv = bf2f(g[(size_t)v * 64 + lane]);
    int i0 = e0 + lane;
    int2 pr = ep[i0 < N_EDGES ? i0 : (N_EDGES - 1)];
    while (v < N_NODES) {
        int vn = v + nw;
        int e0n = 0, e1n = 0;
        float dvn = 0.0f, hvn = 0.0f;
        int2 prn = make_int2(0, 0);
        if (vn < N_NODES) {
            e0n = rowptr[vn]; e1n = rowptr[vn + 1];
            dvn = dinv[vn];
            hvn = bf2f(g[(size_t)vn * 64 + lane]);
            int in0 = e0n + lane;
            prn = ep[in0 < N_EDGES ? in0 : (N_EDGES - 1)];
        }
        float acc = dv * hv;
        acc = agg_node(e0, e1, pr, ep, g, lane, acc);
        float m = dv * acc + bb;                    // mu (lanes<32) / lv (hi)
        float t = expf(0.5f * m) * eps[(size_t)v * Z_DIM + f];
        float tlo = __shfl(t, lane | 32);
        size_t o = (size_t)v * Z_DIM + f;
        if (!hi) { mu[o] = m; z[o] = m + tlo; }
        else     { lv[o] = m; }
        v = vn; e0 = e0n; e1 = e1n; dv = dvn; hv = hvn; pr = prn;
    }
}

// ---------------------------------------------------------------------------
extern "C" void kernel_launch(void* const* d_in, const int* in_sizes, int n_in,
                              void* d_out, int out_size, void* d_ws, size_t ws_size,
                              hipStream_t stream) {
    const float* x   = (const float*)d_in[0];
    const void*  ei  = d_in[1];
    const float* W1  = (const float*)d_in[2];
    const float* b1  = (const float*)d_in[3];
    const float* W2  = (const float*)d_in[4];
    const float* b2  = (const float*)d_in[5];
    const float* Wmu = (const float*)d_in[6];
    const float* bmu = (const float*)d_in[7];
    const float* Wlv = (const float*)d_in[8];
    const float* blv = (const float*)d_in[9];
    const float* eps = (const float*)d_in[10];
    float* out = (float*)d_out;
    (void)in_sizes; (void)n_in; (void)out_size; (void)ws_size;

    char* ws = (char*)d_ws;
    size_t off = 0;
    auto alloc = [&](size_t bytes) -> void* {
        void* p = ws + off;
        off += (bytes + 255) & ~(size_t)255;
        return p;
    };
    int2*           ep     = (int2*)alloc(sizeof(int2) * N_EDGES);   // 6.4 MB
    int*            rowptr = (int*)alloc(sizeof(int) * (N_NODES + 1));
    int*            cursor = (int*)alloc(sizeof(int) * N_NODES);
    int*            cnt    = (int*)alloc(sizeof(int) * N_NODES);
    float*          dinv   = (float*)alloc(sizeof(float) * N_NODES);
    int*            flag   = (int*)alloc(sizeof(int) * 64);
    int*            bsum   = (int*)alloc(sizeof(int) * 256);
    unsigned short* xb     = (unsigned short*)alloc(sizeof(short) * (size_t)N_NODES * IN_DIM);  // 3.2 MB
    unsigned short* G      = (unsigned short*)alloc(sizeof(short) * (size_t)N_NODES * HIDDEN);  // 6.4 MB
    unsigned short* H      = (unsigned short*)alloc(sizeof(short) * (size_t)N_NODES * HIDDEN);  // 6.4 MB

    hipMemsetAsync(cnt, 0, sizeof(int) * N_NODES, stream);
    prep_kernel<<<(N_NODES * IN_DIM + 255) / 256, 256, 0, stream>>>(x, xb, ei, flag, cnt);
    scan1_kernel<<<NB_SCAN, SCAN_B, 0, stream>>>(cnt, rowptr, bsum, dinv);
    scan23_kernel<<<NB_SCAN, SCAN_B, 0, stream>>>(rowptr, bsum, cursor);
    scatter_gemm1_kernel<<<SCAT_B + FB, 256, 0, stream>>>(ei, flag, dinv, cursor, ep,
                                                          xb, W1, G);
    // Layer 1 agg: h1 = relu(A g1 + b1)
    agg_layer_kernel<<<FB, 256, 0, stream>>>(rowptr, ep, dinv, G, b1, H);
    // Layer 2: g2 = h1 @ W2 ; h2 = relu(A g2 + b2)
    gemm_kernel<HIDDEN><<<FB, 256, 0, stream>>>(H, W2, G);
    agg_layer_kernel<<<FB, 256, 0, stream>>>(rowptr, ep, dinv, G, b2, H);
    // Heads: gH = h2 @ [Wmu|Wlv] ; [mu|lv] = A gH + b ; z = mu + exp(.5 lv) eps
    gemm_head_kernel<<<FB, 256, 0, stream>>>(H, Wmu, Wlv, G);
    agg_head_kernel<<<FB, 256, 0, stream>>>(rowptr, ep, dinv, G, bmu, blv, eps, out);
}

// Round 13
// 296.526 us; speedup vs baseline: 1.1766x; 1.0548x over previous
//
#include <hip/hip_runtime.h>
#include <hip/hip_bf16.h>
#include <math.h>

#define N_NODES 50000
#define N_EDGES 800000
#define IN_DIM 32
#define HIDDEN 64
#define Z_DIM 32
#define SCAN_B 256
#define NB_SCAN ((N_NODES + SCAN_B - 1) / SCAN_B)   // 196
#define N_XCD 8
#define NPX ((N_NODES + N_XCD - 1) / N_XCD)         // 6250 nodes per XCD range
#define SLICE 2048
#define N_SLICE ((N_EDGES + SLICE - 1) / SLICE)     // 391
#define SCAT_B (N_SLICE * N_XCD)                    // 3128 scatter blocks
#define FB 2048                                     // 8192 waves for node kernels

// bf16 (stored as ushort) <-> f32 helpers, RNE
__device__ __forceinline__ float bf2f(unsigned short u) {
    return __uint_as_float(((unsigned int)u) << 16);
}
__device__ __forceinline__ unsigned short f2bf(float f) {
    unsigned int u = __float_as_uint(f);
    u += 0x7fffu + ((u >> 16) & 1u);
    return (unsigned short)(u >> 16);
}

// wave-local edge dtype detect: int64 LE values < 2^31 have all-zero odd words.
__device__ __forceinline__ int detect64(const int* raw) {
    int lane = threadIdx.x & 63;
    int odd = raw[2 * lane + 1];
    unsigned long long b = __ballot(odd != 0);
    return (b == 0ULL) ? 1 : 0;
}

// ---------------------------------------------------------------------------
// prep: x->bf16 convert + XCD-partitioned degree histogram + publish flag.
// Blocks < SCAT_B also run a hist slice: xcd = b%8 owns dst range
// [xcd*NPX, (xcd+1)*NPX) -> cnt atomics stay local to one XCD's L2.
__global__ void prep_kernel(const float* __restrict__ x, unsigned short* __restrict__ xb,
                            const void* __restrict__ raw, int* __restrict__ flag,
                            int* __restrict__ cnt) {
    int is64 = detect64((const int*)raw);
    int i = blockIdx.x * 256 + threadIdx.x;
    if (blockIdx.x == 0 && threadIdx.x == 0) *flag = is64;
    if (i < N_NODES * IN_DIM) xb[i] = f2bf(x[i]);
    if (blockIdx.x < SCAT_B) {
        int xcd = blockIdx.x % N_XCD;
        int sl  = blockIdx.x / N_XCD;
        int lo  = xcd * NPX, hi = lo + NPX;
        int base = sl * SLICE;
#pragma unroll
        for (int j = 0; j < SLICE / 256; j++) {
            int e = base + j * 256 + threadIdx.x;
            if (e < N_EDGES) {
                int d = is64 ? (int)((const long long*)raw)[N_EDGES + e]
                             : ((const int*)raw)[N_EDGES + e];
                if (d >= lo && d < hi) atomicAdd(&cnt[d], 1);
            }
        }
    }
}

// ---------------------------------------------------------------------------
// scan1: block-local exclusive scan of cnt -> pre, block sums, dinv.
__global__ void scan1_kernel(const int* __restrict__ cnt, int* __restrict__ pre,
                             int* __restrict__ bsum, float* __restrict__ dinv) {
    __shared__ int s[SCAN_B];
    int t = threadIdx.x;
    int g = blockIdx.x * SCAN_B + t;
    int v = (g < N_NODES) ? cnt[g] : 0;
    if (g < N_NODES) dinv[g] = rsqrtf((float)(v + 1));   // +1 self loop
    s[t] = v;
    __syncthreads();
    for (int o = 1; o < SCAN_B; o <<= 1) {
        int add = (t >= o) ? s[t - o] : 0;
        __syncthreads();
        s[t] += add;
        __syncthreads();
    }
    if (g < N_NODES) pre[g] = s[t] - v;
    if (t == SCAN_B - 1) bsum[blockIdx.x] = s[t];
}

// scan23: each block redundantly scans the 196 bsums in LDS, applies offset.
__global__ void scan23_kernel(int* __restrict__ rowptr, const int* __restrict__ bsum,
                              int* __restrict__ cursor) {
    __shared__ int s[256];
    int t = threadIdx.x;
    int v = (t < NB_SCAN) ? bsum[t] : 0;
    s[t] = v;
    __syncthreads();
    for (int o = 1; o < 256; o <<= 1) {
        int add = (t >= o) ? s[t - o] : 0;
        __syncthreads();
        s[t] += add;
        __syncthreads();
    }
    int excl = s[blockIdx.x] - bsum[blockIdx.x];
    int g = blockIdx.x * SCAN_B + t;
    if (g < N_NODES) {
        int r = rowptr[g] + excl;
        rowptr[g] = r;
        cursor[g] = r;
    }
    if (g == 0) rowptr[N_NODES] = N_EDGES;
}

// ---------------------------------------------------------------------------
// Fused XCD-partitioned scatter + gemm1.
// Blocks [0, SCAT_B): xcd = b%8 processes slice b/8, keeping only edges whose
// dst is in its node range -> ep-line writes and cursor atomics stay in one
// XCD's L2 (kills cross-XCD partial-line ping-pong). Each edge read 8x
// (sequential, cheap), written once.
// Blocks [SCAT_B, SCAT_B+FB): g1 = xb @ W1.
__global__ __launch_bounds__(256) void scatter_gemm1_kernel(
        const void* __restrict__ raw, const int* __restrict__ flag,
        const float* __restrict__ dinv, int* __restrict__ cursor,
        int2* __restrict__ ep,
        const unsigned short* __restrict__ xb, const float* __restrict__ W1,
        unsigned short* __restrict__ G) {
    if (blockIdx.x < SCAT_B) {
        int is64 = *flag;
        int xcd = blockIdx.x % N_XCD;
        int sl  = blockIdx.x / N_XCD;
        int lo  = xcd * NPX, hi = lo + NPX;
        int base = sl * SLICE;
#pragma unroll
        for (int j = 0; j < SLICE / 256; j++) {
            int e = base + j * 256 + threadIdx.x;
            if (e >= N_EDGES) continue;
            int s, d;
            if (is64) {
                s = (int)((const long long*)raw)[e];
                d = (int)((const long long*)raw)[N_EDGES + e];
            } else {
                s = ((const int*)raw)[e];
                d = ((const int*)raw)[N_EDGES + e];
            }
            if (d >= lo && d < hi) {
                float w = dinv[s];
                int p = atomicAdd(&cursor[d], 1);
                ep[p] = make_int2(s, __float_as_int(w));
            }
        }
    } else {
        int lane = threadIdx.x & 63;
        float wcol[IN_DIM];
#pragma unroll
        for (int k = 0; k < IN_DIM; k++) wcol[k] = W1[k * 64 + lane];
        int bid = blockIdx.x - SCAT_B;
        int wid = __builtin_amdgcn_readfirstlane((int)((bid * 256 + threadIdx.x) >> 6));
        int nw  = (FB * 256) >> 6;
        for (int v = wid; v < N_NODES; v += nw) {
            const uint4* rp = (const uint4*)(xb + (size_t)v * IN_DIM);
            float a0 = 0.0f, a1 = 0.0f;
#pragma unroll
            for (int c = 0; c < IN_DIM / 8; c++) {
                uint4 r = rp[c];
                a0 = fmaf(__uint_as_float(r.x << 16),         wcol[c * 8 + 0], a0);
                a1 = fmaf(__uint_as_float(r.x & 0xffff0000u), wcol[c * 8 + 1], a1);
                a0 = fmaf(__uint_as_float(r.y << 16),         wcol[c * 8 + 2], a0);
                a1 = fmaf(__uint_as_float(r.y & 0xffff0000u), wcol[c * 8 + 3], a1);
                a0 = fmaf(__uint_as_float(r.z << 16),         wcol[c * 8 + 4], a0);
                a1 = fmaf(__uint_as_float(r.z & 0xffff0000u), wcol[c * 8 + 5], a1);
                a0 = fmaf(__uint_as_float(r.w << 16),         wcol[c * 8 + 6], a0);
                a1 = fmaf(__uint_as_float(r.w & 0xffff0000u), wcol[c * 8 + 7], a1);
            }
            G[(size_t)v * 64 + lane] = f2bf(a0 + a1);
        }
    }
}

// ---------------------------------------------------------------------------
// Dense GEMM: out[v][lane] = sum_k in[v][k] * W[k][lane].  (bias lives in agg)
template<int DIN>
__global__ __launch_bounds__(256) void gemm_kernel(const unsigned short* __restrict__ in,
                                                   const float* __restrict__ W,
                                                   unsigned short* __restrict__ out) {
    int lane = threadIdx.x & 63;
    float wcol[DIN];
#pragma unroll
    for (int k = 0; k < DIN; k++) wcol[k] = W[k * 64 + lane];
    int wid = __builtin_amdgcn_readfirstlane((int)((blockIdx.x * blockDim.x + threadIdx.x) >> 6));
    int nw  = (gridDim.x * blockDim.x) >> 6;
    for (int v = wid; v < N_NODES; v += nw) {
        const uint4* rp = (const uint4*)(in + (size_t)v * DIN);   // uniform ptr
        float a0 = 0.0f, a1 = 0.0f;
#pragma unroll
        for (int c = 0; c < DIN / 8; c++) {
            uint4 r = rp[c];
            a0 = fmaf(__uint_as_float(r.x << 16),         wcol[c * 8 + 0], a0);
            a1 = fmaf(__uint_as_float(r.x & 0xffff0000u), wcol[c * 8 + 1], a1);
            a0 = fmaf(__uint_as_float(r.y << 16),         wcol[c * 8 + 2], a0);
            a1 = fmaf(__uint_as_float(r.y & 0xffff0000u), wcol[c * 8 + 3], a1);
            a0 = fmaf(__uint_as_float(r.z << 16),         wcol[c * 8 + 4], a0);
            a1 = fmaf(__uint_as_float(r.z & 0xffff0000u), wcol[c * 8 + 5], a1);
            a0 = fmaf(__uint_as_float(r.w << 16),         wcol[c * 8 + 6], a0);
            a1 = fmaf(__uint_as_float(r.w & 0xffff0000u), wcol[c * 8 + 7], a1);
        }
        out[(size_t)v * 64 + lane] = f2bf(a0 + a1);
    }
}

// Heads GEMM: out[v][lane] = h2[v][:] @ (lane<32 ? Wmu[:,lane] : Wlv[:,lane-32])
__global__ __launch_bounds__(256) void gemm_head_kernel(const unsigned short* __restrict__ in,
                                                        const float* __restrict__ Wmu,
                                                        const float* __restrict__ Wlv,
                                                        unsigned short* __restrict__ out) {
    int lane = threadIdx.x & 63;
    int f = lane & 31;
    float wcol[64];
#pragma unroll
    for (int k = 0; k < 64; k++)
        wcol[k] = (lane < 32) ? Wmu[k * 32 + f] : Wlv[k * 32 + f];
    int wid = __builtin_amdgcn_readfirstlane((int)((blockIdx.x * blockDim.x + threadIdx.x) >> 6));
    int nw  = (gridDim.x * blockDim.x) >> 6;
    for (int v = wid; v < N_NODES; v += nw) {
        const uint4* rp = (const uint4*)(in + (size_t)v * 64);
        float a0 = 0.0f, a1 = 0.0f;
#pragma unroll
        for (int c = 0; c < 8; c++) {
            uint4 r = rp[c];
            a0 = fmaf(__uint_as_float(r.x << 16),         wcol[c * 8 + 0], a0);
            a1 = fmaf(__uint_as_float(r.x & 0xffff0000u), wcol[c * 8 + 1], a1);
            a0 = fmaf(__uint_as_float(r.y << 16),         wcol[c * 8 + 2], a0);
            a1 = fmaf(__uint_as_float(r.y & 0xffff0000u), wcol[c * 8 + 3], a1);
            a0 = fmaf(__uint_as_float(r.z << 16),         wcol[c * 8 + 4], a0);
            a1 = fmaf(__uint_as_float(r.z & 0xffff0000u), wcol[c * 8 + 5], a1);
            a0 = fmaf(__uint_as_float(r.w << 16),         wcol[c * 8 + 6], a0);
            a1 = fmaf(__uint_as_float(r.w & 0xffff0000u), wcol[c * 8 + 7], a1);
        }
        out[(size_t)v * 64 + lane] = f2bf(a0 + a1);
    }
}

// ---------------------------------------------------------------------------
// Process one node's edges given a prefetched first ep batch pr0.
// 16-deep main chunks, masked-8 tail (guard-free), extra batches inline.
__device__ __forceinline__ float agg_node(int e0, int e1, int2 pr0,
                                          const int2* __restrict__ ep,
                                          const unsigned short* __restrict__ g,
                                          int lane, float acc) {
    int2 pr = pr0;
    for (int base = e0; base < e1; base += 64) {
        int cnt = e1 - base; cnt = cnt > 64 ? 64 : cnt;      // uniform
        int j = 0;
        for (; j + 16 <= cnt; j += 16) {                     // full 16-chunks
            float f[16], w[16];
#pragma unroll
            for (int u = 0; u < 16; u++) {
                int jj = j + u;
                int   s = __builtin_amdgcn_readlane(pr.x, jj);
                w[u]    = __int_as_float(__builtin_amdgcn_readlane(pr.y, jj));
                f[u]    = bf2f(g[(size_t)s * 64 + lane]);
            }
#pragma unroll
            for (int u = 0; u < 16; u++) acc = fmaf(w[u], f[u], acc);
        }
        for (; j < cnt; j += 8) {                            // masked 8-tail
            float f[8], w[8];
#pragma unroll
            for (int u = 0; u < 8; u++) {
                int jj = j + u;
                int   s = __builtin_amdgcn_readlane(pr.x, jj < 63 ? jj : 63);
                float wv = __int_as_float(__builtin_amdgcn_readlane(pr.y, jj < 63 ? jj : 63));
                w[u]    = (jj < cnt) ? wv : 0.0f;            // uniform select
                f[u]    = bf2f(g[(size_t)s * 64 + lane]);
            }
#pragma unroll
            for (int u = 0; u < 8; u++) acc = fmaf(w[u], f[u], acc);
        }
        int nb = base + 64;
        if (nb < e1) {                                       // rare extra batch
            int idx = nb + lane;
            pr = ep[idx < N_EDGES ? idx : (N_EDGES - 1)];
        }
    }
    return acc;
}

// Aggregation with next-node software pipeline.
__global__ __launch_bounds__(256) void agg_layer_kernel(
        const int* __restrict__ rowptr, const int2* __restrict__ ep,
        const float* __restrict__ dinv, const unsigned short* __restrict__ g,
        const float* __restrict__ bias, unsigned short* __restrict__ out) {
    int lane = threadIdx.x & 63;
    float bb = bias[lane];
    int wid = __builtin_amdgcn_readfirstlane((int)((blockIdx.x * blockDim.x + threadIdx.x) >> 6));
    int nw  = (gridDim.x * blockDim.x) >> 6;
    int v = wid;
    if (v >= N_NODES) return;
    int e0 = rowptr[v], e1 = rowptr[v + 1];
    float dv = dinv[v];
    float hv = bf2f(g[(size_t)v * 64 + lane]);
    int i0 = e0 + lane;
    int2 pr = ep[i0 < N_EDGES ? i0 : (N_EDGES - 1)];
    while (v < N_NODES) {
        int vn = v + nw;
        int e0n = 0, e1n = 0;
        float dvn = 0.0f, hvn = 0.0f;
        int2 prn = make_int2(0, 0);
        if (vn < N_NODES) {                                  // prefetch next node
            e0n = rowptr[vn]; e1n = rowptr[vn + 1];
            dvn = dinv[vn];
            hvn = bf2f(g[(size_t)vn * 64 + lane]);
            int in0 = e0n + lane;
            prn = ep[in0 < N_EDGES ? in0 : (N_EDGES - 1)];
        }
        float acc = dv * hv;
        acc = agg_node(e0, e1, pr, ep, g, lane, acc);
        out[(size_t)v * 64 + lane] = f2bf(fmaxf(dv * acc + bb, 0.0f));
        v = vn; e0 = e0n; e1 = e1n; dv = dvn; hv = hvn; pr = prn;
    }
}

// Head aggregation + reparam. g packed [gmu | glv]; d_out = [z | mu | lv] fp32.
__global__ __launch_bounds__(256) void agg_head_kernel(
        const int* __restrict__ rowptr, const int2* __restrict__ ep,
        const float* __restrict__ dinv, const unsigned short* __restrict__ g,
        const float* __restrict__ bmu, const float* __restrict__ blv,
        const float* __restrict__ eps, float* __restrict__ outz) {
    int lane = threadIdx.x & 63;
    int f = lane & 31;
    bool hi = lane >= 32;
    float bb = hi ? blv[f] : bmu[f];
    float* z  = outz;
    float* mu = outz + (size_t)N_NODES * Z_DIM;
    float* lv = outz + 2 * (size_t)N_NODES * Z_DIM;
    int wid = __builtin_amdgcn_readfirstlane((int)((blockIdx.x * blockDim.x + threadIdx.x) >> 6));
    int nw  = (gridDim.x * blockDim.x) >> 6;
    int v = wid;
    if (v >= N_NODES) return;
    int e0 = rowptr[v], e1 = rowptr[v + 1];
    float dv = dinv[v];
    float hv = bf2f(g[(size_t)v * 64 + lane]);
    int i0 = e0 + lane;
    int2 pr = ep[i0 < N_EDGES ? i0 : (N_EDGES - 1)];
    while (v < N_NODES) {
        int vn = v + nw;
        int e0n = 0, e1n = 0;
        float dvn = 0.0f, hvn = 0.0f;
        int2 prn = make_int2(0, 0);
        if (vn < N_NODES) {
            e0n = rowptr[vn]; e1n = rowptr[vn + 1];
            dvn = dinv[vn];
            hvn = bf2f(g[(size_t)vn * 64 + lane]);
            int in0 = e0n + lane;
            prn = ep[in0 < N_EDGES ? in0 : (N_EDGES - 1)];
        }
        float acc = dv * hv;
        acc = agg_node(e0, e1, pr, ep, g, lane, acc);
        float m = dv * acc + bb;                    // mu (lanes<32) / lv (hi)
        float t = expf(0.5f * m) * eps[(size_t)v * Z_DIM + f];
        float tlo = __shfl(t, lane | 32);
        size_t o = (size_t)v * Z_DIM + f;
        if (!hi) { mu[o] = m; z[o] = m + tlo; }
        else     { lv[o] = m; }
        v = vn; e0 = e0n; e1 = e1n; dv = dvn; hv = hvn; pr = prn;
    }
}

// ---------------------------------------------------------------------------
extern "C" void kernel_launch(void* const* d_in, const int* in_sizes, int n_in,
                              void* d_out, int out_size, void* d_ws, size_t ws_size,
                              hipStream_t stream) {
    const float* x   = (const float*)d_in[0];
    const void*  ei  = d_in[1];
    const float* W1  = (const float*)d_in[2];
    const float* b1  = (const float*)d_in[3];
    const float* W2  = (const float*)d_in[4];
    const float* b2  = (const float*)d_in[5];
    const float* Wmu = (const float*)d_in[6];
    const float* bmu = (const float*)d_in[7];
    const float* Wlv = (const float*)d_in[8];
    const float* blv = (const float*)d_in[9];
    const float* eps = (const float*)d_in[10];
    float* out = (float*)d_out;
    (void)in_sizes; (void)n_in; (void)out_size; (void)ws_size;

    char* ws = (char*)d_ws;
    size_t off = 0;
    auto alloc = [&](size_t bytes) -> void* {
        void* p = ws + off;
        off += (bytes + 255) & ~(size_t)255;
        return p;
    };
    int2*           ep     = (int2*)alloc(sizeof(int2) * N_EDGES);   // 6.4 MB
    int*            rowptr = (int*)alloc(sizeof(int) * (N_NODES + 1));
    int*            cursor = (int*)alloc(sizeof(int) * N_NODES);
    int*            cnt    = (int*)alloc(sizeof(int) * N_NODES);
    float*          dinv   = (float*)alloc(sizeof(float) * N_NODES);
    int*            flag   = (int*)alloc(sizeof(int) * 64);
    int*            bsum   = (int*)alloc(sizeof(int) * 256);
    unsigned short* xb     = (unsigned short*)alloc(sizeof(short) * (size_t)N_NODES * IN_DIM);  // 3.2 MB
    unsigned short* G      = (unsigned short*)alloc(sizeof(short) * (size_t)N_NODES * HIDDEN);  // 6.4 MB
    unsigned short* H      = (unsigned short*)alloc(sizeof(short) * (size_t)N_NODES * HIDDEN);  // 6.4 MB

    hipMemsetAsync(cnt, 0, sizeof(int) * N_NODES, stream);
    prep_kernel<<<(N_NODES * IN_DIM + 255) / 256, 256, 0, stream>>>(x, xb, ei, flag, cnt);
    scan1_kernel<<<NB_SCAN, SCAN_B, 0, stream>>>(cnt, rowptr, bsum, dinv);
    scan23_kernel<<<NB_SCAN, SCAN_B, 0, stream>>>(rowptr, bsum, cursor);
    scatter_gemm1_kernel<<<SCAT_B + FB, 256, 0, stream>>>(ei, flag, dinv, cursor, ep,
                                                          xb, W1, G);
    // Layer 1 agg: h1 = relu(A g1 + b1)
    agg_layer_kernel<<<FB, 256, 0, stream>>>(rowptr, ep, dinv, G, b1, H);
    // Layer 2: g2 = h1 @ W2 ; h2 = relu(A g2 + b2)
    gemm_kernel<HIDDEN><<<FB, 256, 0, stream>>>(H, W2, G);
    agg_layer_kernel<<<FB, 256, 0, stream>>>(rowptr, ep, dinv, G, b2, H);
    // Heads: gH = h2 @ [Wmu|Wlv] ; [mu|lv] = A gH + b ; z = mu + exp(.5 lv) eps
    gemm_head_kernel<<<FB, 256, 0, stream>>>(H, Wmu, Wlv, G);
    agg_head_kernel<<<FB, 256, 0, stream>>>(rowptr, ep, dinv, G, bmu, blv, eps, out);
}